// Round 6
// baseline (201.469 us; speedup 1.0000x reference)
//
#include <hip/hip_runtime.h>

#define BATCH  8192
#define LATENT 128
#define HID    400
#define HIDP   448   // 7*64, zero-padded K for layer 2
#define NOUT   4096
#define NE     16
#define HROWS  (BATCH + 128)   // padded rows so layer-2 A-staging never reads OOB

typedef __attribute__((ext_vector_type(8))) short bf16x8;
typedef __attribute__((ext_vector_type(4))) float f32x4;

__device__ __forceinline__ unsigned short f2bf(float f){
  unsigned u = __builtin_bit_cast(unsigned, f);
  u += 0x7fffu + ((u >> 16) & 1u);            // round-to-nearest-even
  return (unsigned short)(u >> 16);
}

__device__ __forceinline__ void gload16(const void* g, void* l){
  __builtin_amdgcn_global_load_lds(
      (const __attribute__((address_space(1))) void*)g,
      (__attribute__((address_space(3))) void*)l, 16, 0, 0);
}

// ---------------- bucketing: hist + scan + scatter, one block ----------------
__global__ __launch_bounds__(1024) void k_bucket(const int* __restrict__ aidx, int* __restrict__ wsI){
  __shared__ int hist[NE];
  __shared__ int cursor[NE];
  int tid = threadIdx.x, lane = tid & 63;
  if (tid < NE) hist[tid] = 0;
  __syncthreads();

  int ev[8];
  #pragma unroll
  for (int c=0;c<8;c++) ev[c] = aidx[c*1024 + tid];

  #pragma unroll
  for (int c=0;c<8;c++){
    for (int x=0;x<NE;x++){
      unsigned long long m = __ballot(ev[c]==x);
      if (lane==0 && m) atomicAdd(&hist[x], (int)__popcll(m));
    }
  }
  __syncthreads();
  if (tid==0){
    int a=0;
    for (int x=0;x<NE;x++){ cursor[x]=a; wsI[32+x]=a; a+=hist[x]; }
    wsI[32+NE]=a;
  }
  __syncthreads();

  #pragma unroll
  for (int c=0;c<8;c++){
    int e = ev[c], i = c*1024 + tid;
    for (int x=0;x<NE;x++){
      unsigned long long m = __ballot(e==x);
      if (m){
        int leader = __ffsll((unsigned long long)m) - 1;
        int base = 0;
        if (lane == leader) base = atomicAdd(&cursor[x], (int)__popcll(m));
        base = __shfl(base, leader);
        if (e==x){
          int rank = (int)__popcll(m & ((1ull<<lane)-1ull));
          wsI[64 + base + rank] = i;
        }
      }
    }
  }
}

// ---------------- mid: blocks 0..1007 = layer1 tiles; blocks 1008.. = W2 fp32->bf16 ----------------
// layer1: h = relu(z @ W1[e]^T + b1[e]); convert: W2b[e][n][k] padded to HIDP.
__global__ __launch_bounds__(256) void k_mid(
    const float* __restrict__ z, const float* __restrict__ W1, const float* __restrict__ b1,
    const int* __restrict__ wsI, unsigned short* __restrict__ hws,
    const float* __restrict__ W2, unsigned short* __restrict__ W2b)
{
  int tid = threadIdx.x;
  if (blockIdx.x >= 1008){
    // ---- convert: 16384 blocks x 4 rows ----
    int row  = (int)(blockIdx.x - 1008)*4 + (tid>>6);
    int slot = tid & 63;
    if (slot >= 56) return;
    int k = slot*8;
    bf16x8 wv = (bf16x8){0,0,0,0,0,0,0,0};
    if (k < HID){
      const float* s = W2 + (size_t)row*HID + k;
      float4 a = *(const float4*)s, b = *(const float4*)(s+4);
      wv[0]=(short)f2bf(a.x); wv[1]=(short)f2bf(a.y); wv[2]=(short)f2bf(a.z); wv[3]=(short)f2bf(a.w);
      wv[4]=(short)f2bf(b.x); wv[5]=(short)f2bf(b.y); wv[6]=(short)f2bf(b.z); wv[7]=(short)f2bf(b.w);
    }
    *(bf16x8*)(W2b + (size_t)row*HIDP + k) = wv;
    return;
  }

  // ---- layer 1 ----
  __shared__ int s_off[NE+1];
  __shared__ int s_perm[64];
  __shared__ unsigned short As[64*128];
  __shared__ unsigned short Bs[64*128];
  if (tid <= NE) s_off[tid] = wsI[32+tid];
  __syncthreads();

  int rt = (int)blockIdx.x / 7;
  int n0 = ((int)blockIdx.x % 7) * 64;

  int e=-1, tile=0;
  { int acc=0;
    for (int i=0;i<NE;i++){
      int cnt = s_off[i+1]-s_off[i]; int t = (cnt+63)>>6;
      if (rt < acc+t){ e=i; tile=rt-acc; break; }
      acc += t; } }
  if (e < 0) return;
  int r0 = s_off[e] + tile*64;
  int rows = s_off[e+1] - r0; if (rows > 64) rows = 64;

  if (tid < 64) s_perm[tid] = (tid < rows) ? wsI[64 + r0 + tid] : 0;
  __syncthreads();

  #pragma unroll
  for (int p=0;p<8;p++){
    int id = tid + p*256; int row = id>>5, c4 = id&31;
    float4 v = make_float4(0.f,0.f,0.f,0.f);
    if (row < rows) v = *(const float4*)(z + (size_t)s_perm[row]*LATENT + c4*4);
    short4 w; w.x=(short)f2bf(v.x); w.y=(short)f2bf(v.y); w.z=(short)f2bf(v.z); w.w=(short)f2bf(v.w);
    *(short4*)((char*)As + row*256 + ((c4*8) ^ ((row&7)<<4))) = w;
  }
  const float* w1e = W1 + (size_t)e*HID*LATENT;
  #pragma unroll
  for (int p=0;p<8;p++){
    int id = tid + p*256; int row = id>>5, c4 = id&31;
    int n = n0 + row;
    float4 v = make_float4(0.f,0.f,0.f,0.f);
    if (n < HID) v = *(const float4*)(w1e + (size_t)n*LATENT + c4*4);
    short4 w; w.x=(short)f2bf(v.x); w.y=(short)f2bf(v.y); w.z=(short)f2bf(v.z); w.w=(short)f2bf(v.w);
    *(short4*)((char*)Bs + row*256 + ((c4*8) ^ ((row&7)<<4))) = w;
  }
  __syncthreads();

  int lane = tid & 63, wid = tid >> 6;
  int wm = wid >> 1, wn = wid & 1;
  int llo = lane & 15, lhi = lane >> 4;
  f32x4 acc[2][2];
  #pragma unroll
  for (int i=0;i<2;i++)
    #pragma unroll
    for (int j=0;j<2;j++) acc[i][j] = (f32x4){0.f,0.f,0.f,0.f};

  #pragma unroll
  for (int s=0;s<4;s++){
    bf16x8 af[2], bfr[2];
    #pragma unroll
    for (int i=0;i<2;i++){ int m = wm*32 + i*16 + llo;
      af[i] = *(bf16x8*)((char*)As + m*256 + ((s*64 + lhi*16) ^ ((m&7)<<4))); }
    #pragma unroll
    for (int j=0;j<2;j++){ int n = wn*32 + j*16 + llo;
      bfr[j] = *(bf16x8*)((char*)Bs + n*256 + ((s*64 + lhi*16) ^ ((n&7)<<4))); }
    #pragma unroll
    for (int i=0;i<2;i++)
      #pragma unroll
      for (int j=0;j<2;j++)
        acc[i][j] = __builtin_amdgcn_mfma_f32_16x16x32_bf16(af[i], bfr[j], acc[i][j], 0,0,0);
  }

  const float* b1e = b1 + e*HID;
  #pragma unroll
  for (int i=0;i<2;i++){
    #pragma unroll
    for (int j=0;j<2;j++){
      int n = n0 + wn*32 + j*16 + llo;
      float bias = (n < HID) ? b1e[n] : 0.f;
      #pragma unroll
      for (int q=0;q<4;q++){
        int m = wm*32 + i*16 + lhi*4 + q;
        if (m < rows){
          float v = acc[i][j][q] + bias;
          v = (v > 0.f) ? v : 0.f;
          if (n >= HID) v = 0.f;
          hws[(size_t)(r0+m)*HIDP + n] = f2bf(v);
        }
      }
    }
  }
}

// ---------------- layer 2: out = sigmoid(h @ W2b[e]^T + b2[e]) ----------------
// 128x128 tile, BK=32, plane LDS [4 units][128 rows][16B], double-buffered
// global_load_lds with COUNTED vmcnt across raw barriers (loads stay in flight).
__global__ __launch_bounds__(256) void k_layer2(
    const unsigned short* __restrict__ hws, const unsigned short* __restrict__ W2b,
    const float* __restrict__ b2, const int* __restrict__ wsI, float* __restrict__ out)
{
  __shared__ int s_off[NE+1];
  __shared__ int s_perm[128];
  __shared__ unsigned short As[2][4096];
  __shared__ unsigned short Bs[2][4096];
  int tid = threadIdx.x;
  if (tid <= NE) s_off[tid] = wsI[32+tid];
  __syncthreads();

  int e=-1, tile=0;
  { int acc=0;
    for (int i=0;i<NE;i++){
      int cnt = s_off[i+1]-s_off[i]; int t = (cnt+127)>>7;
      if ((int)blockIdx.x < acc+t){ e=i; tile=(int)blockIdx.x-acc; break; }
      acc += t; } }
  if (e < 0) return;
  int r0 = s_off[e] + tile*128;
  int rows = s_off[e+1] - r0; if (rows > 128) rows = 128;
  int n0 = blockIdx.y * 128;
  if (tid < 128) s_perm[tid] = (tid < rows) ? wsI[64 + r0 + tid] : 0;

  // staging: load slot a in [0,512): LDS element a*8 -> unit u=a>>7, row r=a&127.
  int a0 = tid, a1 = tid + 256;
  const unsigned short* aS0 = hws + (size_t)(r0 + (a0 & 127))*HIDP + (a0>>7)*8;
  const unsigned short* aS1 = hws + (size_t)(r0 + (a1 & 127))*HIDP + (a1>>7)*8;
  const unsigned short* bS0 = W2b + ((size_t)e*NOUT + n0 + (a0 & 127))*HIDP + (a0>>7)*8;
  const unsigned short* bS1 = W2b + ((size_t)e*NOUT + n0 + (a1 & 127))*HIDP + (a1>>7)*8;

  int lane = tid & 63, w = tid >> 6;
  int wm = w >> 1, wn = w & 1;
  int llo = lane & 15, lhi = lane >> 4;
  int uoff = lhi*1024;      // element offset of K-unit plane (128 rows * 8 el)
  f32x4 acc[4][4];
  #pragma unroll
  for (int i=0;i<4;i++)
    #pragma unroll
    for (int j=0;j<4;j++) acc[i][j] = (f32x4){0.f,0.f,0.f,0.f};

  #define STAGE(BUF, K0) { \
    gload16(aS0 + (K0), &As[BUF][a0*8]); \
    gload16(aS1 + (K0), &As[BUF][a1*8]); \
    gload16(bS0 + (K0), &Bs[BUF][a0*8]); \
    gload16(bS1 + (K0), &Bs[BUF][a1*8]); }

  STAGE(0, 0);

  int cur = 0;
  for (int kt=0; kt<14; kt++){
    if (kt < 13){
      STAGE(cur^1, (kt+1)*32);
      asm volatile("s_waitcnt vmcnt(4)" ::: "memory");   // cur's 4 landed; next's 4 in flight
    } else {
      asm volatile("s_waitcnt vmcnt(0)" ::: "memory");
    }
    __builtin_amdgcn_s_barrier();
    bf16x8 af[4], bfr[4];
    #pragma unroll
    for (int i=0;i<4;i++){ int m = wm*64 + i*16 + llo;
      af[i] = *(bf16x8*)(&As[cur][uoff + m*8]); }
    #pragma unroll
    for (int j=0;j<4;j++){ int n = wn*64 + j*16 + llo;
      bfr[j] = *(bf16x8*)(&Bs[cur][uoff + n*8]); }
    #pragma unroll
    for (int i=0;i<4;i++)
      #pragma unroll
      for (int j=0;j<4;j++)
        acc[i][j] = __builtin_amdgcn_mfma_f32_16x16x32_bf16(af[i], bfr[j], acc[i][j], 0,0,0);
    __builtin_amdgcn_s_barrier();    // protect cur from next iter's overwrite
    cur ^= 1;
  }

  const float* b2e = b2 + e*NOUT;
  #pragma unroll
  for (int i=0;i<4;i++){
    int mb = wm*64 + i*16 + lhi*4;
    #pragma unroll
    for (int q=0;q<4;q++){
      int m = mb + q;
      if (m < rows){
        int orow = s_perm[m];
        float* op = out + (size_t)orow*NOUT + n0;
        #pragma unroll
        for (int j=0;j<4;j++){
          int nloc = wn*64 + j*16 + llo;
          float x = acc[i][j][q] + b2e[n0 + nloc];
          op[nloc] = 1.f / (1.f + __expf(-x));
        }
      }
    }
  }
}

extern "C" void kernel_launch(void* const* d_in, const int* in_sizes, int n_in,
                              void* d_out, int out_size, void* d_ws, size_t ws_size,
                              hipStream_t stream){
  const float* z   = (const float*)d_in[0];
  const float* W1  = (const float*)d_in[1];
  const float* b1  = (const float*)d_in[2];
  const float* W2  = (const float*)d_in[3];
  const float* b2  = (const float*)d_in[4];
  const int*  aidx = (const int*)d_in[5];
  float* out = (float*)d_out;
  int* wsI = (int*)d_ws;
  unsigned short* hws = (unsigned short*)((char*)d_ws + 65536);
  unsigned short* W2b = (unsigned short*)((char*)d_ws + 65536 + (size_t)HROWS*HIDP*2);

  k_bucket<<<1, 1024, 0, stream>>>(aidx, wsI);
  k_mid   <<<1008 + 16384, 256, 0, stream>>>(z, W1, b1, wsI, hws, W2, W2b);
  k_layer2<<<dim3(80, 32), 256, 0, stream>>>(hws, W2b, b2, wsI, out);
}

// Round 7
// 177.121 us; speedup vs baseline: 1.1375x; 1.1375x over previous
//
#include <hip/hip_runtime.h>

#define BATCH  8192
#define LATENT 128
#define HID    400
#define HIDP   448   // 7*64, zero-padded K for layer 2
#define NOUT   4096
#define NE     16
#define HROWS  (BATCH + 128)   // padded rows so layer-2 A-staging never reads OOB

typedef __attribute__((ext_vector_type(8))) short bf16x8;
typedef __attribute__((ext_vector_type(4))) float f32x4;

__device__ __forceinline__ unsigned short f2bf(float f){
  unsigned u = __builtin_bit_cast(unsigned, f);
  u += 0x7fffu + ((u >> 16) & 1u);            // round-to-nearest-even
  return (unsigned short)(u >> 16);
}

__device__ __forceinline__ void gload16(const void* g, void* l){
  __builtin_amdgcn_global_load_lds(
      (const __attribute__((address_space(1))) void*)g,
      (__attribute__((address_space(3))) void*)l, 16, 0, 0);
}

// ---------------- prep: block 0 = bucket (hist+scan+scatter); blocks 1.. = W2 fp32->bf16 ----------------
__global__ __launch_bounds__(1024) void k_prep(
    const int* __restrict__ aidx, int* __restrict__ wsI,
    const float* __restrict__ W2, unsigned short* __restrict__ W2b)
{
  int tid = threadIdx.x;
  if (blockIdx.x != 0){
    // convert: 4096 blocks x 16 rows; row-local slot of 8 cols
    int row  = (int)(blockIdx.x - 1)*16 + (tid>>6);
    int slot = tid & 63;
    if (slot >= 56) return;
    int k = slot*8;
    bf16x8 w = (bf16x8){0,0,0,0,0,0,0,0};
    if (k < HID){
      const float* s = W2 + (size_t)row*HID + k;
      float4 a = *(const float4*)s, b = *(const float4*)(s+4);
      w[0]=(short)f2bf(a.x); w[1]=(short)f2bf(a.y); w[2]=(short)f2bf(a.z); w[3]=(short)f2bf(a.w);
      w[4]=(short)f2bf(b.x); w[5]=(short)f2bf(b.y); w[6]=(short)f2bf(b.z); w[7]=(short)f2bf(b.w);
    }
    *(bf16x8*)(W2b + (size_t)row*HIDP + k) = w;
    return;
  }
  // bucket
  __shared__ int hist[NE];
  __shared__ int cursor[NE];
  int lane = tid & 63;
  if (tid < NE) hist[tid] = 0;
  __syncthreads();

  int ev[8];
  #pragma unroll
  for (int c=0;c<8;c++) ev[c] = aidx[c*1024 + tid];

  #pragma unroll
  for (int c=0;c<8;c++){
    for (int x=0;x<NE;x++){
      unsigned long long m = __ballot(ev[c]==x);
      if (lane==0 && m) atomicAdd(&hist[x], (int)__popcll(m));
    }
  }
  __syncthreads();
  if (tid==0){
    int a=0;
    for (int x=0;x<NE;x++){ cursor[x]=a; wsI[32+x]=a; a+=hist[x]; }
    wsI[32+NE]=a;
  }
  __syncthreads();

  #pragma unroll
  for (int c=0;c<8;c++){
    int e = ev[c], i = c*1024 + tid;
    for (int x=0;x<NE;x++){
      unsigned long long m = __ballot(e==x);
      if (m){
        int leader = __ffsll((unsigned long long)m) - 1;
        int base = 0;
        if (lane == leader) base = atomicAdd(&cursor[x], (int)__popcll(m));
        base = __shfl(base, leader);
        if (e==x){
          int rank = (int)__popcll(m & ((1ull<<lane)-1ull));
          wsI[64 + base + rank] = i;
        }
      }
    }
  }
}

// ---------------- layer 1: h = relu(z @ W1[e]^T + b1[e]) ----------------
__global__ __launch_bounds__(256) void k_layer1(
    const float* __restrict__ z, const float* __restrict__ W1, const float* __restrict__ b1,
    const int* __restrict__ wsI, unsigned short* __restrict__ hws)
{
  __shared__ int s_off[NE+1];
  __shared__ int s_perm[64];
  __shared__ unsigned short As[64*128];
  __shared__ unsigned short Bs[64*128];
  int tid = threadIdx.x;
  if (tid <= NE) s_off[tid] = wsI[32+tid];
  __syncthreads();

  int e=-1, tile=0;
  { int acc=0;
    for (int i=0;i<NE;i++){
      int cnt = s_off[i+1]-s_off[i]; int t = (cnt+63)>>6;
      if ((int)blockIdx.x < acc+t){ e=i; tile=(int)blockIdx.x-acc; break; }
      acc += t; } }
  if (e < 0) return;
  int r0 = s_off[e] + tile*64;
  int rows = s_off[e+1] - r0; if (rows > 64) rows = 64;
  int n0 = blockIdx.y * 64;

  if (tid < 64) s_perm[tid] = (tid < rows) ? wsI[64 + r0 + tid] : 0;
  __syncthreads();

  #pragma unroll
  for (int p=0;p<8;p++){
    int id = tid + p*256; int row = id>>5, c4 = id&31;
    float4 v = make_float4(0.f,0.f,0.f,0.f);
    if (row < rows) v = *(const float4*)(z + (size_t)s_perm[row]*LATENT + c4*4);
    short4 w; w.x=(short)f2bf(v.x); w.y=(short)f2bf(v.y); w.z=(short)f2bf(v.z); w.w=(short)f2bf(v.w);
    *(short4*)((char*)As + row*256 + ((c4*8) ^ ((row&7)<<4))) = w;
  }
  const float* w1e = W1 + (size_t)e*HID*LATENT;
  #pragma unroll
  for (int p=0;p<8;p++){
    int id = tid + p*256; int row = id>>5, c4 = id&31;
    int n = n0 + row;
    float4 v = make_float4(0.f,0.f,0.f,0.f);
    if (n < HID) v = *(const float4*)(w1e + (size_t)n*LATENT + c4*4);
    short4 w; w.x=(short)f2bf(v.x); w.y=(short)f2bf(v.y); w.z=(short)f2bf(v.z); w.w=(short)f2bf(v.w);
    *(short4*)((char*)Bs + row*256 + ((c4*8) ^ ((row&7)<<4))) = w;
  }
  __syncthreads();

  int lane = tid & 63, wid = tid >> 6;
  int wm = wid >> 1, wn = wid & 1;
  int llo = lane & 15, lhi = lane >> 4;
  f32x4 acc[2][2];
  #pragma unroll
  for (int i=0;i<2;i++)
    #pragma unroll
    for (int j=0;j<2;j++) acc[i][j] = (f32x4){0.f,0.f,0.f,0.f};

  #pragma unroll
  for (int s=0;s<4;s++){
    bf16x8 af[2], bfr[2];
    #pragma unroll
    for (int i=0;i<2;i++){ int m = wm*32 + i*16 + llo;
      af[i] = *(bf16x8*)((char*)As + m*256 + ((s*64 + lhi*16) ^ ((m&7)<<4))); }
    #pragma unroll
    for (int j=0;j<2;j++){ int n = wn*32 + j*16 + llo;
      bfr[j] = *(bf16x8*)((char*)Bs + n*256 + ((s*64 + lhi*16) ^ ((n&7)<<4))); }
    #pragma unroll
    for (int i=0;i<2;i++)
      #pragma unroll
      for (int j=0;j<2;j++)
        acc[i][j] = __builtin_amdgcn_mfma_f32_16x16x32_bf16(af[i], bfr[j], acc[i][j], 0,0,0);
  }

  const float* b1e = b1 + e*HID;
  #pragma unroll
  for (int i=0;i<2;i++){
    #pragma unroll
    for (int j=0;j<2;j++){
      int n = n0 + wn*32 + j*16 + llo;
      float bias = (n < HID) ? b1e[n] : 0.f;
      #pragma unroll
      for (int q=0;q<4;q++){
        int m = wm*32 + i*16 + lhi*4 + q;
        if (m < rows){
          float v = acc[i][j][q] + bias;
          v = (v > 0.f) ? v : 0.f;
          if (n >= HID) v = 0.f;
          hws[(size_t)(r0+m)*HIDP + n] = f2bf(v);
        }
      }
    }
  }
}

// ---------------- layer 2: out = sigmoid(h @ W2b[e]^T + b2[e]) ----------------
// 128x128 tile, BK=32, plane LDS [4 units][128 rows][16B], ring-4 buffers,
// depth-2 prefetch with counted vmcnt, 1 barrier/iter, XCD-chunked swizzle.
__global__ __launch_bounds__(256) void k_layer2(
    const unsigned short* __restrict__ hws, const unsigned short* __restrict__ W2b,
    const float* __restrict__ b2, const int* __restrict__ wsI, float* __restrict__ out)
{
  __shared__ int s_off[NE+1];
  __shared__ int s_perm[128];
  __shared__ unsigned short As[4][4096];
  __shared__ unsigned short Bs[4][4096];
  int tid = threadIdx.x;
  if (tid <= NE) s_off[tid] = wsI[32+tid];
  __syncthreads();

  // XCD-chunked swizzle: 2560 blocks, 8 XCDs, 320/XCD; x-fastest within y so
  // same-expert row-tiles (sharing a B n-tile) co-locate on one XCD's L2.
  int lin = (int)blockIdx.x;
  int logical = (lin & 7) * 320 + (lin >> 3);
  int bx = logical % 80, by = logical / 80;

  int e=-1, tile=0;
  { int acc=0;
    for (int i=0;i<NE;i++){
      int cnt = s_off[i+1]-s_off[i]; int t = (cnt+127)>>7;
      if (bx < acc+t){ e=i; tile=bx-acc; break; }
      acc += t; } }
  if (e < 0) return;
  int r0 = s_off[e] + tile*128;
  int rows = s_off[e+1] - r0; if (rows > 128) rows = 128;
  int n0 = by * 128;
  if (tid < 128) s_perm[tid] = (tid < rows) ? wsI[64 + r0 + tid] : 0;

  // staging: load slot a in [0,512): LDS element a*8 -> unit u=a>>7, row r=a&127.
  int a0 = tid, a1 = tid + 256;
  const unsigned short* aS0 = hws + (size_t)(r0 + (a0 & 127))*HIDP + (a0>>7)*8;
  const unsigned short* aS1 = hws + (size_t)(r0 + (a1 & 127))*HIDP + (a1>>7)*8;
  const unsigned short* bS0 = W2b + ((size_t)e*NOUT + n0 + (a0 & 127))*HIDP + (a0>>7)*8;
  const unsigned short* bS1 = W2b + ((size_t)e*NOUT + n0 + (a1 & 127))*HIDP + (a1>>7)*8;

  int lane = tid & 63, w = tid >> 6;
  int wm = w >> 1, wn = w & 1;
  int llo = lane & 15, lhi = lane >> 4;
  int uoff = lhi*1024;      // element offset of K-unit plane (128 rows * 8 el)
  f32x4 acc[4][4];
  #pragma unroll
  for (int i=0;i<4;i++)
    #pragma unroll
    for (int j=0;j<4;j++) acc[i][j] = (f32x4){0.f,0.f,0.f,0.f};

  #define STAGE(BUF, K0) { \
    gload16(aS0 + (K0), &As[BUF][a0*8]); \
    gload16(aS1 + (K0), &As[BUF][a1*8]); \
    gload16(bS0 + (K0), &Bs[BUF][a0*8]); \
    gload16(bS1 + (K0), &Bs[BUF][a1*8]); }

  // prologue: 2 tiles in flight
  STAGE(0, 0);
  STAGE(1, 32);

  for (int kt=0; kt<14; kt++){
    if (kt < 12){
      STAGE((kt+2)&3, (kt+2)*32);
      asm volatile("s_waitcnt vmcnt(8)" ::: "memory");   // kt's 4 landed; kt+1,kt+2 in flight
    } else if (kt == 12){
      asm volatile("s_waitcnt vmcnt(4)" ::: "memory");
    } else {
      asm volatile("s_waitcnt vmcnt(0)" ::: "memory");
    }
    __builtin_amdgcn_s_barrier();
    const unsigned short* Ab = &As[kt&3][0];
    const unsigned short* Bb = &Bs[kt&3][0];
    bf16x8 af[4], bfr[4];
    #pragma unroll
    for (int i=0;i<4;i++){ int m = wm*64 + i*16 + llo;
      af[i] = *(bf16x8*)(Ab + uoff + m*8); }
    #pragma unroll
    for (int j=0;j<4;j++){ int n = wn*64 + j*16 + llo;
      bfr[j] = *(bf16x8*)(Bb + uoff + n*8); }
    #pragma unroll
    for (int i=0;i<4;i++)
      #pragma unroll
      for (int j=0;j<4;j++)
        acc[i][j] = __builtin_amdgcn_mfma_f32_16x16x32_bf16(af[i], bfr[j], acc[i][j], 0,0,0);
  }

  const float* b2e = b2 + e*NOUT;
  #pragma unroll
  for (int i=0;i<4;i++){
    int mb = wm*64 + i*16 + lhi*4;
    #pragma unroll
    for (int q=0;q<4;q++){
      int m = mb + q;
      if (m < rows){
        int orow = s_perm[m];
        float* op = out + (size_t)orow*NOUT + n0;
        #pragma unroll
        for (int j=0;j<4;j++){
          int nloc = wn*64 + j*16 + llo;
          float x = acc[i][j][q] + b2e[n0 + nloc];
          op[nloc] = 1.f / (1.f + __expf(-x));
        }
      }
    }
  }
}

extern "C" void kernel_launch(void* const* d_in, const int* in_sizes, int n_in,
                              void* d_out, int out_size, void* d_ws, size_t ws_size,
                              hipStream_t stream){
  const float* z   = (const float*)d_in[0];
  const float* W1  = (const float*)d_in[1];
  const float* b1  = (const float*)d_in[2];
  const float* W2  = (const float*)d_in[3];
  const float* b2  = (const float*)d_in[4];
  const int*  aidx = (const int*)d_in[5];
  float* out = (float*)d_out;
  int* wsI = (int*)d_ws;
  unsigned short* hws = (unsigned short*)((char*)d_ws + 65536);
  unsigned short* W2b = (unsigned short*)((char*)d_ws + 65536 + (size_t)HROWS*HIDP*2);

  k_prep  <<<4097, 1024, 0, stream>>>(aidx, wsI, W2, W2b);
  k_layer1<<<dim3(144, 7), 256, 0, stream>>>(z, W1, b1, wsI, hws);
  k_layer2<<<2560, 256, 0, stream>>>(hws, W2b, b2, wsI, out);
}

// Round 8
// 164.061 us; speedup vs baseline: 1.2280x; 1.0796x over previous
//
#include <hip/hip_runtime.h>

#define BATCH  8192
#define LATENT 128
#define HID    400
#define HIDP   448   // 7*64, zero-padded K for layer 2
#define NOUT   4096
#define NE     16
#define HROWS  (BATCH + 128)   // padded rows so layer-2 A-staging never reads OOB

typedef __attribute__((ext_vector_type(8))) short bf16x8;
typedef __attribute__((ext_vector_type(4))) float f32x4;

__device__ __forceinline__ unsigned short f2bf(float f){
  unsigned u = __builtin_bit_cast(unsigned, f);
  u += 0x7fffu + ((u >> 16) & 1u);            // round-to-nearest-even
  return (unsigned short)(u >> 16);
}

__device__ __forceinline__ void gload16(const void* g, void* l){
  __builtin_amdgcn_global_load_lds(
      (const __attribute__((address_space(1))) void*)g,
      (__attribute__((address_space(3))) void*)l, 16, 0, 0);
}

__device__ __forceinline__ void convert_rows(const float* __restrict__ W2,
                                             unsigned short* __restrict__ W2b,
                                             int row, int slot){
  if (slot >= 56) return;
  int k = slot*8;
  bf16x8 w = (bf16x8){0,0,0,0,0,0,0,0};
  if (k < HID){
    const float* s = W2 + (size_t)row*HID + k;
    float4 a = *(const float4*)s, b = *(const float4*)(s+4);
    w[0]=(short)f2bf(a.x); w[1]=(short)f2bf(a.y); w[2]=(short)f2bf(a.z); w[3]=(short)f2bf(a.w);
    w[4]=(short)f2bf(b.x); w[5]=(short)f2bf(b.y); w[6]=(short)f2bf(b.z); w[7]=(short)f2bf(b.w);
  }
  *(bf16x8*)(W2b + (size_t)row*HIDP + k) = w;
}

// ---------------- prep: block 0 = bucket; blocks 1..1728 = convert rows 0..27647 ----------------
__global__ __launch_bounds__(1024) void k_prep(
    const int* __restrict__ aidx, int* __restrict__ wsI,
    const float* __restrict__ W2, unsigned short* __restrict__ W2b)
{
  int tid = threadIdx.x;
  if (blockIdx.x != 0){
    int row  = (int)(blockIdx.x - 1)*16 + (tid>>6);
    convert_rows(W2, W2b, row, tid & 63);
    return;
  }
  __shared__ int hist[NE];
  __shared__ int cursor[NE];
  int lane = tid & 63;
  if (tid < NE) hist[tid] = 0;
  __syncthreads();

  int ev[8];
  #pragma unroll
  for (int c=0;c<8;c++) ev[c] = aidx[c*1024 + tid];

  #pragma unroll
  for (int c=0;c<8;c++){
    for (int x=0;x<NE;x++){
      unsigned long long m = __ballot(ev[c]==x);
      if (lane==0 && m) atomicAdd(&hist[x], (int)__popcll(m));
    }
  }
  __syncthreads();
  if (tid==0){
    int a=0;
    for (int x=0;x<NE;x++){ cursor[x]=a; wsI[32+x]=a; a+=hist[x]; }
    wsI[32+NE]=a;
  }
  __syncthreads();

  #pragma unroll
  for (int c=0;c<8;c++){
    int e = ev[c], i = c*1024 + tid;
    for (int x=0;x<NE;x++){
      unsigned long long m = __ballot(e==x);
      if (m){
        int leader = __ffsll((unsigned long long)m) - 1;
        int base = 0;
        if (lane == leader) base = atomicAdd(&cursor[x], (int)__popcll(m));
        base = __shfl(base, leader);
        if (e==x){
          int rank = (int)__popcll(m & ((1ull<<lane)-1ull));
          wsI[64 + base + rank] = i;
        }
      }
    }
  }
}

// ---------------- mid: blocks 0..1007 = layer1; blocks 1008.. = convert rows 27648..65535 ----------------
__global__ __launch_bounds__(256) void k_mid(
    const float* __restrict__ z, const float* __restrict__ W1, const float* __restrict__ b1,
    const int* __restrict__ wsI, unsigned short* __restrict__ hws,
    const float* __restrict__ W2, unsigned short* __restrict__ W2b)
{
  int tid = threadIdx.x;
  if (blockIdx.x >= 1008){
    int row = 27648 + (int)(blockIdx.x - 1008)*4 + (tid>>6);
    convert_rows(W2, W2b, row, tid & 63);
    return;
  }

  // ---- layer 1 ----
  __shared__ int s_off[NE+1];
  __shared__ int s_perm[64];
  __shared__ unsigned short As[64*128];
  __shared__ unsigned short Bs[64*128];
  if (tid <= NE) s_off[tid] = wsI[32+tid];
  __syncthreads();

  int rt = (int)blockIdx.x / 7;
  int n0 = ((int)blockIdx.x % 7) * 64;

  int e=-1, tile=0;
  { int acc=0;
    for (int i=0;i<NE;i++){
      int cnt = s_off[i+1]-s_off[i]; int t = (cnt+63)>>6;
      if (rt < acc+t){ e=i; tile=rt-acc; break; }
      acc += t; } }
  if (e < 0) return;
  int r0 = s_off[e] + tile*64;
  int rows = s_off[e+1] - r0; if (rows > 64) rows = 64;

  if (tid < 64) s_perm[tid] = (tid < rows) ? wsI[64 + r0 + tid] : 0;
  __syncthreads();

  #pragma unroll
  for (int p=0;p<8;p++){
    int id = tid + p*256; int row = id>>5, c4 = id&31;
    float4 v = make_float4(0.f,0.f,0.f,0.f);
    if (row < rows) v = *(const float4*)(z + (size_t)s_perm[row]*LATENT + c4*4);
    short4 w; w.x=(short)f2bf(v.x); w.y=(short)f2bf(v.y); w.z=(short)f2bf(v.z); w.w=(short)f2bf(v.w);
    *(short4*)((char*)As + row*256 + ((c4*8) ^ ((row&7)<<4))) = w;
  }
  const float* w1e = W1 + (size_t)e*HID*LATENT;
  #pragma unroll
  for (int p=0;p<8;p++){
    int id = tid + p*256; int row = id>>5, c4 = id&31;
    int n = n0 + row;
    float4 v = make_float4(0.f,0.f,0.f,0.f);
    if (n < HID) v = *(const float4*)(w1e + (size_t)n*LATENT + c4*4);
    short4 w; w.x=(short)f2bf(v.x); w.y=(short)f2bf(v.y); w.z=(short)f2bf(v.z); w.w=(short)f2bf(v.w);
    *(short4*)((char*)Bs + row*256 + ((c4*8) ^ ((row&7)<<4))) = w;
  }
  __syncthreads();

  int lane = tid & 63, wid = tid >> 6;
  int wm = wid >> 1, wn = wid & 1;
  int llo = lane & 15, lhi = lane >> 4;
  f32x4 acc[2][2];
  #pragma unroll
  for (int i=0;i<2;i++)
    #pragma unroll
    for (int j=0;j<2;j++) acc[i][j] = (f32x4){0.f,0.f,0.f,0.f};

  #pragma unroll
  for (int s=0;s<4;s++){
    bf16x8 af[2], bfr[2];
    #pragma unroll
    for (int i=0;i<2;i++){ int m = wm*32 + i*16 + llo;
      af[i] = *(bf16x8*)((char*)As + m*256 + ((s*64 + lhi*16) ^ ((m&7)<<4))); }
    #pragma unroll
    for (int j=0;j<2;j++){ int n = wn*32 + j*16 + llo;
      bfr[j] = *(bf16x8*)((char*)Bs + n*256 + ((s*64 + lhi*16) ^ ((n&7)<<4))); }
    #pragma unroll
    for (int i=0;i<2;i++)
      #pragma unroll
      for (int j=0;j<2;j++)
        acc[i][j] = __builtin_amdgcn_mfma_f32_16x16x32_bf16(af[i], bfr[j], acc[i][j], 0,0,0);
  }

  const float* b1e = b1 + e*HID;
  #pragma unroll
  for (int i=0;i<2;i++){
    #pragma unroll
    for (int j=0;j<2;j++){
      int n = n0 + wn*32 + j*16 + llo;
      float bias = (n < HID) ? b1e[n] : 0.f;
      #pragma unroll
      for (int q=0;q<4;q++){
        int m = wm*32 + i*16 + lhi*4 + q;
        if (m < rows){
          float v = acc[i][j][q] + bias;
          v = (v > 0.f) ? v : 0.f;
          if (n >= HID) v = 0.f;
          hws[(size_t)(r0+m)*HIDP + n] = f2bf(v);
        }
      }
    }
  }
}

// ---------------- layer 2: out = sigmoid(h @ W2b[e]^T + b2[e]) ----------------
// 128x128 tile, BK=64 (7 iters), XOR-swizzled LDS via pre-swizzled gload_lds src,
// double-buffered with COUNTED vmcnt(8): next tile's 8 loads stay in flight
// across both barriers. XCD-chunked block swizzle (2560 = 8*320, bijective).
__global__ __launch_bounds__(256) void k_layer2(
    const unsigned short* __restrict__ hws, const unsigned short* __restrict__ W2b,
    const float* __restrict__ b2, const int* __restrict__ wsI, float* __restrict__ out)
{
  __shared__ int s_off[NE+1];
  __shared__ int s_perm[128];
  __shared__ unsigned short As[2][128*64];
  __shared__ unsigned short Bs[2][128*64];
  int tid = threadIdx.x;
  if (tid <= NE) s_off[tid] = wsI[32+tid];
  __syncthreads();

  int lin = (int)blockIdx.x;
  int logical = (lin & 7) * 320 + (lin >> 3);
  int bx = logical % 80, by = logical / 80;

  int e=-1, tile=0;
  { int acc=0;
    for (int i=0;i<NE;i++){
      int cnt = s_off[i+1]-s_off[i]; int t = (cnt+127)>>7;
      if (bx < acc+t){ e=i; tile=bx-acc; break; }
      acc += t; } }
  if (e < 0) return;
  int r0 = s_off[e] + tile*128;
  int rows = s_off[e+1] - r0; if (rows > 128) rows = 128;
  int n0 = by * 128;
  if (tid < 128) s_perm[tid] = (tid < rows) ? wsI[64 + r0 + tid] : 0;

  int lane = tid & 63, w = tid >> 6;
  // staging: 16 chunks of 1KB per matrix; wave w stages chunks w*4+p.
  // lane -> row-in-chunk = lane>>3, dest 16B-unit = lane&7; source col unit
  // pre-swizzled: colU = (lane&7) ^ (lane>>3)  (since row&7 == lane>>3).
  int srow = lane >> 3;
  int colU = (lane & 7) ^ srow;
  const unsigned short* aSrcBase = hws + (size_t)r0*HIDP + colU*8;
  const unsigned short* bSrcBase = W2b + ((size_t)e*NOUT + n0)*HIDP + colU*8;

  int wm = w >> 1, wn = w & 1;
  int llo = lane & 15, lhi = lane >> 4;
  f32x4 acc[4][4];
  #pragma unroll
  for (int i=0;i<4;i++)
    #pragma unroll
    for (int j=0;j<4;j++) acc[i][j] = (f32x4){0.f,0.f,0.f,0.f};

  #define STAGE(BUF, K0) { _Pragma("unroll") for (int p=0;p<4;p++){ \
      int c = w*4 + p; int row = c*8 + srow; \
      gload16(aSrcBase + (size_t)row*HIDP + (K0), &As[BUF][c*512]); \
      gload16(bSrcBase + (size_t)row*HIDP + (K0), &Bs[BUF][c*512]); } }

  STAGE(0, 0);
  asm volatile("s_waitcnt vmcnt(0)" ::: "memory");
  __builtin_amdgcn_s_barrier();

  int cur = 0;
  for (int kt=0; kt<7; kt++){
    if (kt < 6){
      STAGE(cur^1, (kt+1)*64);          // 8 loads for next tile, left in flight
    }
    #pragma unroll
    for (int s=0;s<2;s++){
      bf16x8 af[4], bfr[4];
      #pragma unroll
      for (int i=0;i<4;i++){ int m = wm*64 + i*16 + llo;
        af[i] = *(bf16x8*)((char*)&As[cur][0] + m*128 + ((s*64 + lhi*16) ^ ((m&7)<<4))); }
      #pragma unroll
      for (int j=0;j<4;j++){ int n = wn*64 + j*16 + llo;
        bfr[j] = *(bf16x8*)((char*)&Bs[cur][0] + n*128 + ((s*64 + lhi*16) ^ ((n&7)<<4))); }
      #pragma unroll
      for (int i=0;i<4;i++)
        #pragma unroll
        for (int j=0;j<4;j++)
          acc[i][j] = __builtin_amdgcn_mfma_f32_16x16x32_bf16(af[i], bfr[j], acc[i][j], 0,0,0);
    }
    // done reading cur; wait own next-tile loads (8 in flight -> landed), publish
    if (kt < 6){
      asm volatile("s_waitcnt vmcnt(8)" ::: "memory");
    }
    __builtin_amdgcn_s_barrier();       // all waves done reading cur & their loads landed
    cur ^= 1;
  }

  const float* b2e = b2 + e*NOUT;
  #pragma unroll
  for (int i=0;i<4;i++){
    int mb = wm*64 + i*16 + lhi*4;
    #pragma unroll
    for (int q=0;q<4;q++){
      int m = mb + q;
      if (m < rows){
        int orow = s_perm[m];
        float* op = out + (size_t)orow*NOUT + n0;
        #pragma unroll
        for (int j=0;j<4;j++){
          int nloc = wn*64 + j*16 + llo;
          float x = acc[i][j][q] + b2e[n0 + nloc];
          op[nloc] = 1.f / (1.f + __expf(-x));
        }
      }
    }
  }
}

extern "C" void kernel_launch(void* const* d_in, const int* in_sizes, int n_in,
                              void* d_out, int out_size, void* d_ws, size_t ws_size,
                              hipStream_t stream){
  const float* z   = (const float*)d_in[0];
  const float* W1  = (const float*)d_in[1];
  const float* b1  = (const float*)d_in[2];
  const float* W2  = (const float*)d_in[3];
  const float* b2  = (const float*)d_in[4];
  const int*  aidx = (const int*)d_in[5];
  float* out = (float*)d_out;
  int* wsI = (int*)d_ws;
  unsigned short* hws = (unsigned short*)((char*)d_ws + 65536);
  unsigned short* W2b = (unsigned short*)((char*)d_ws + 65536 + (size_t)HROWS*HIDP*2);

  k_prep  <<<1729, 1024, 0, stream>>>(aidx, wsI, W2, W2b);          // bucket || convert rows 0..27647
  k_mid   <<<1008 + 9472, 256, 0, stream>>>(z, W1, b1, wsI, hws, W2, W2b); // layer1 || convert rest
  k_layer2<<<2560, 256, 0, stream>>>(hws, W2b, b2, wsI, out);
}